// Round 4
// baseline (20907.770 us; speedup 1.0000x reference)
//
#include <hip/hip_runtime.h>
#include <math.h>

// SARABrainCore R4: fp64 internals (proven R3: zero spike flips vs np-fp64 ref,
// absmax 0.0039). Perf rewrite of the GEMM core:
//  - v1 bottleneck: SQ_LDS_BANK_CONFLICT = 1e8/dispatch (~29% of CU cycles),
//    from 4-way-conflicted fp64 B-fragment LDS reads. VALUBusy 42%.
//  - v2: LDS holds only A (k-major, pad 66 -> 2-way stores = free; frag reads
//    are 16-lane broadcasts = conflict-free), double-buffered, 1 barrier/iter,
//    register prefetch. B streamed per-kk from global (fp32 weights, L1-hot).
//  - LayerNorm fused: stats kernel writes (mu, rstd); ctx recomputed on the fly
//    in gate's A-loader/epilogue. ctx array eliminated.
// Accumulation order per output element is bit-identical to R3.

#define BB 1024
#define TT 16
#define DD 1024
#define HH 2048
#define OO 1024
#define PAD 66

struct D4 { double x, y, z, w; };

// ---- A-side loaders: 4 consecutive-k fp64 values, row pre-bound ----
struct Ld4F {               // fp32 row (x input)
    const float* r;
    __device__ __forceinline__ D4 load4(int k) const {
        const float4 f = *(const float4*)(r + k);
        return {(double)f.x, (double)f.y, (double)f.z, (double)f.w};
    }
};
struct Ld4D {               // fp64 row (gated / attr)
    const double* r;
    __device__ __forceinline__ D4 load4(int k) const {
        const double2 a = *(const double2*)(r + k);
        const double2 b = *(const double2*)(r + k + 2);
        return {a.x, a.y, b.x, b.y};
    }
};
struct Ld4LN {              // a2 = ctx + rec computed on the fly
    const double* r; const float* g; const float* be; double mu, rs;
    __device__ __forceinline__ D4 load4(int k) const {
        const double2 a = *(const double2*)(r + k);
        const double2 b = *(const double2*)(r + k + 2);
        const float4 gf = *(const float4*)(g + k);
        const float4 bf = *(const float4*)(be + k);
        D4 o;
        o.x = (a.x - mu)*rs*(double)gf.x + (double)bf.x + a.x;
        o.y = (a.y - mu)*rs*(double)gf.y + (double)bf.y + a.y;
        o.z = (b.x - mu)*rs*(double)gf.z + (double)bf.z + b.x;
        o.w = (b.y - mu)*rs*(double)gf.w + (double)bf.w + b.y;
        return o;
    }
};
struct Ld4Spk {             // spike count -> mean (x0.0625 exact)
    const float* r;
    __device__ __forceinline__ D4 load4(int k) const {
        const float4 f = *(const float4*)(r + k);
        return {(double)f.x*0.0625, (double)f.y*0.0625,
                (double)f.z*0.0625, (double)f.w*0.0625};
    }
};

// ---- B-side loaders: 4 consecutive-n values at row k (global stream) ----
struct LdBF {               // fp32 weights [K][N]
    const float* p; long ldb;
    __device__ __forceinline__ D4 load4(int k, int n) const {
        const float4 f = *(const float4*)(p + (long)k*ldb + n);
        return {(double)f.x, (double)f.y, (double)f.z, (double)f.w};
    }
};
struct LdBD {               // fp64 weights [K][N] (Wpf)
    const double* p; long ldb;
    __device__ __forceinline__ D4 load4(int k, int n) const {
        const double2 a = *(const double2*)(p + (long)k*ldb + n);
        const double2 b = *(const double2*)(p + (long)k*ldb + n + 2);
        return {a.x, a.y, b.x, b.y};
    }
};

// ---- GEMM core: 64x64 tile, 256 thr, 4x4/thr, BK=16, A-LDS dbuf, B streamed.
// Per-element accumulation: k strictly ascending (bit-identical to R3).
template<typename ALd, typename BLd>
__device__ __forceinline__ void gemm2(const ALd& A, const BLd& B, int col0,
                                      int niter, double (*As)[16*PAD],
                                      double acc[4][4])
{
    const int tid = threadIdx.x;
    const int tx = tid & 15, ty = tid >> 4;
    const int am = tid >> 2, ak = (tid & 3) << 2;
    const int bn = col0 + tx*4;

    D4 ap = A.load4(ak);                       // prologue: stage k-tile 0
    As[0][(ak+0)*PAD + am] = ap.x;
    As[0][(ak+1)*PAD + am] = ap.y;
    As[0][(ak+2)*PAD + am] = ap.z;
    As[0][(ak+3)*PAD + am] = ap.w;
    __syncthreads();

    int cur = 0;
    for (int it = 0; it < niter; ++it) {
        const int k0 = it*16;
        const bool more = (it + 1 < niter);
        if (more) ap = A.load4(k0 + 16 + ak);  // prefetch next A tile to regs
        const double* __restrict__ Ab = As[cur];
        #pragma unroll
        for (int kk = 0; kk < 16; ++kk) {
            const D4 b = B.load4(k0 + kk, bn);
            const double a0 = Ab[kk*PAD + ty*4 + 0];
            const double a1 = Ab[kk*PAD + ty*4 + 1];
            const double a2 = Ab[kk*PAD + ty*4 + 2];
            const double a3 = Ab[kk*PAD + ty*4 + 3];
            acc[0][0] = fma(a0, b.x, acc[0][0]);
            acc[0][1] = fma(a0, b.y, acc[0][1]);
            acc[0][2] = fma(a0, b.z, acc[0][2]);
            acc[0][3] = fma(a0, b.w, acc[0][3]);
            acc[1][0] = fma(a1, b.x, acc[1][0]);
            acc[1][1] = fma(a1, b.y, acc[1][1]);
            acc[1][2] = fma(a1, b.z, acc[1][2]);
            acc[1][3] = fma(a1, b.w, acc[1][3]);
            acc[2][0] = fma(a2, b.x, acc[2][0]);
            acc[2][1] = fma(a2, b.y, acc[2][1]);
            acc[2][2] = fma(a2, b.z, acc[2][2]);
            acc[2][3] = fma(a2, b.w, acc[2][3]);
            acc[3][0] = fma(a3, b.x, acc[3][0]);
            acc[3][1] = fma(a3, b.y, acc[3][1]);
            acc[3][2] = fma(a3, b.z, acc[3][2]);
            acc[3][3] = fma(a3, b.w, acc[3][3]);
        }
        if (more) {                            // store prefetched tile
            double* An = As[cur ^ 1];
            An[(ak+0)*PAD + am] = ap.x;
            An[(ak+1)*PAD + am] = ap.y;
            An[(ak+2)*PAD + am] = ap.z;
            An[(ak+3)*PAD + am] = ap.w;
        }
        __syncthreads();
        cur ^= 1;
    }
}

// ---- Wpf = Wp @ Wfc (once) ----
__global__ __launch_bounds__(256) void k_wpf(const float* __restrict__ Wp,
                                             const float* __restrict__ Wfc,
                                             double* __restrict__ Wpf)
{
    __shared__ double As[2][16*PAD];
    double acc[4][4] = {};
    const int row0 = blockIdx.y*64, col0 = blockIdx.x*64;
    const int am = threadIdx.x >> 2;
    Ld4F A{Wp + (long)(row0 + am)*HH};
    LdBF B{Wfc, HH};
    gemm2(A, B, col0, HH/16, As, acc);
    const int tx = threadIdx.x & 15, ty = threadIdx.x >> 4;
    for (int i = 0; i < 4; i++) for (int j = 0; j < 4; j++)
        Wpf[(long)(row0 + ty*4 + i)*HH + col0 + tx*4 + j] = acc[i][j];
}

// ---- bpf[h] = bp @ Wfc + bfc (once, tiny) ----
__global__ __launch_bounds__(256) void k_bpf(const float* __restrict__ bp,
                                             const float* __restrict__ Wfc,
                                             const float* __restrict__ bfc,
                                             double* __restrict__ bpf)
{
    const int h = blockIdx.x*256 + threadIdx.x;
    double acc = 0.0;
    for (int k = 0; k < HH; ++k)
        acc = fma((double)bp[k], (double)Wfc[(long)k*HH + h], acc);
    bpf[h] = acc + (double)bfc[h];
}

// ---- update = tanh(x_t @ Wpf + bpf); rec = BETA*rec + (1-BETA)*update ----
__global__ __launch_bounds__(256) void k_update(const float* __restrict__ x, int t,
                                                const double* __restrict__ Wpf,
                                                const double* __restrict__ bpf,
                                                double* __restrict__ rec)
{
    __shared__ double As[2][16*PAD];
    double acc[4][4] = {};
    const int row0 = blockIdx.y*64, col0 = blockIdx.x*64;
    const int am = threadIdx.x >> 2;
    Ld4F A{x + (long)(row0 + am)*(TT*DD) + (long)t*DD};
    LdBD B{Wpf, HH};
    gemm2(A, B, col0, DD/16, As, acc);
    const int tx = threadIdx.x & 15, ty = threadIdx.x >> 4;
    const double BETA = 0.9;
    const double OMB  = 1.0 - BETA;   // 0.09999999999999998, Python fp64 semantics
    for (int i = 0; i < 4; i++) for (int j = 0; j < 4; j++) {
        const int b = row0 + ty*4 + i, h = col0 + tx*4 + j;
        const double u = tanh(acc[i][j] + bpf[h]);
        const long idx = (long)b*HH + h;
        rec[idx] = BETA*rec[idx] + OMB*u;
    }
}

// ---- LN stats: mu[b], rstd[b] (same reduction tree as R3) ----
__global__ __launch_bounds__(256) void k_lnstats(const double* __restrict__ rec,
                                                 double* __restrict__ mu,
                                                 double* __restrict__ rstd)
{
    __shared__ double red[256];
    const int b = blockIdx.x, tid = threadIdx.x;
    const double* r = rec + (long)b*HH;
    double s = 0.0;
    for (int h = tid; h < HH; h += 256) s += r[h];
    red[tid] = s; __syncthreads();
    for (int off = 128; off > 0; off >>= 1) {
        if (tid < off) red[tid] += red[tid + off];
        __syncthreads();
    }
    const double mean = red[0] / HH;
    __syncthreads();
    double v = 0.0;
    for (int h = tid; h < HH; h += 256) { const double d = r[h] - mean; v += d*d; }
    red[tid] = v; __syncthreads();
    for (int off = 128; off > 0; off >>= 1) {
        if (tid < off) red[tid] += red[tid + off];
        __syncthreads();
    }
    if (tid == 0) {
        mu[b]   = mean;
        rstd[b] = 1.0 / sqrt(red[0] / HH + 1e-5);
    }
}

// ---- g = sigmoid((ctx+rec) @ Wg + bg); gated = g*ctx + (1-g)*rec ----
__global__ __launch_bounds__(256) void k_gate(const double* __restrict__ rec,
                                              const double* __restrict__ mu,
                                              const double* __restrict__ rstd,
                                              const float* __restrict__ gamma,
                                              const float* __restrict__ beta,
                                              const float* __restrict__ Wg,
                                              const float* __restrict__ bg,
                                              double* __restrict__ gated)
{
    __shared__ double As[2][16*PAD];
    double acc[4][4] = {};
    const int row0 = blockIdx.y*64, col0 = blockIdx.x*64;
    const int am = threadIdx.x >> 2;
    Ld4LN A{rec + (long)(row0 + am)*HH, gamma, beta, mu[row0 + am], rstd[row0 + am]};
    LdBF B{Wg, HH};
    gemm2(A, B, col0, HH/16, As, acc);
    const int tx = threadIdx.x & 15, ty = threadIdx.x >> 4;
    for (int i = 0; i < 4; i++) for (int j = 0; j < 4; j++) {
        const int b = row0 + ty*4 + i, h = col0 + tx*4 + j;
        const long idx = (long)b*HH + h;
        const double r = rec[idx];
        const double ctxv = (r - mu[b])*rstd[b]*(double)gamma[h] + (double)beta[h];
        const double g = 1.0 / (1.0 + exp(-(acc[i][j] + (double)bg[h])));
        gated[idx] = g*ctxv + (1.0 - g)*r;
    }
}

// ---- current = gated@Wenc + attr@Wrec + benc + brec; LIF + spike count ----
__global__ __launch_bounds__(256) void k_current(const double* __restrict__ gated,
                                                 const float* __restrict__ Wenc,
                                                 const double* __restrict__ attr_in,
                                                 const float* __restrict__ Wrec,
                                                 const float* __restrict__ benc,
                                                 const float* __restrict__ brec,
                                                 double* __restrict__ attr_out,
                                                 float* __restrict__ spkcnt)
{
    __shared__ double As[2][16*PAD];
    double acc[4][4] = {};
    const int row0 = blockIdx.y*64, col0 = blockIdx.x*64;
    const int am = threadIdx.x >> 2;
    {
        Ld4D A{gated + (long)(row0 + am)*HH};
        LdBF B{Wenc, HH};
        gemm2(A, B, col0, HH/16, As, acc);
    }
    {
        Ld4D A{attr_in + (long)(row0 + am)*HH};
        LdBF B{Wrec, HH};
        gemm2(A, B, col0, HH/16, As, acc);
    }
    const int tx = threadIdx.x & 15, ty = threadIdx.x >> 4;
    const double TAU = 2.0, THR = 1.0;
    for (int i = 0; i < 4; i++) for (int j = 0; j < 4; j++) {
        const int b = row0 + ty*4 + i, h = col0 + tx*4 + j;
        const long idx = (long)b*HH + h;
        const double cur = acc[i][j] + (double)benc[h] + (double)brec[h];
        const double a  = attr_in[idx];
        const double nv = a + (cur - a)/TAU;
        const double sp = (nv > THR) ? 1.0 : 0.0;
        attr_out[idx] = nv - sp*THR;
        spkcnt[idx] += (float)sp;
    }
}

// ---- out = (spkcnt/16) @ Wro + bro -> fp32 ----
__global__ __launch_bounds__(256) void k_readout(const float* __restrict__ spkcnt,
                                                 const float* __restrict__ Wro,
                                                 const float* __restrict__ bro,
                                                 float* __restrict__ out)
{
    __shared__ double As[2][16*PAD];
    double acc[4][4] = {};
    const int row0 = blockIdx.y*64, col0 = blockIdx.x*64;
    const int am = threadIdx.x >> 2;
    Ld4Spk A{spkcnt + (long)(row0 + am)*HH};
    LdBF B{Wro, OO};
    gemm2(A, B, col0, HH/16, As, acc);
    const int tx = threadIdx.x & 15, ty = threadIdx.x >> 4;
    for (int i = 0; i < 4; i++) for (int j = 0; j < 4; j++) {
        const int b = row0 + ty*4 + i, o = col0 + tx*4 + j;
        out[(long)b*OO + o] = (float)(acc[i][j] + (double)bro[o]);
    }
}

__global__ __launch_bounds__(256) void k_d2f(const double* __restrict__ src,
                                             float* __restrict__ dst)
{
    const long i = (long)blockIdx.x*256 + threadIdx.x;
    dst[i] = (float)src[i];
}

extern "C" void kernel_launch(void* const* d_in, const int* in_sizes, int n_in,
                              void* d_out, int out_size, void* d_ws, size_t ws_size,
                              hipStream_t stream) {
    const float* x    = (const float*)d_in[0];
    const float* Wp   = (const float*)d_in[1];
    const float* bp   = (const float*)d_in[2];
    const float* Wfc  = (const float*)d_in[3];
    const float* bfc  = (const float*)d_in[4];
    const float* gamma= (const float*)d_in[5];
    const float* beta = (const float*)d_in[6];
    const float* Wg   = (const float*)d_in[7];
    const float* bg   = (const float*)d_in[8];
    const float* Wenc = (const float*)d_in[9];
    const float* benc = (const float*)d_in[10];
    const float* Wrec = (const float*)d_in[11];
    const float* brec = (const float*)d_in[12];
    const float* Wro  = (const float*)d_in[13];
    const float* bro  = (const float*)d_in[14];
    float* out = (float*)d_out;

    const long NBH = (long)BB*HH;     // 2M elems
    char* p = (char*)d_ws;
    double* Wpf   = (double*)p; p += (long)DD*HH*sizeof(double);   // 16.8 MB
    double* bpf   = (double*)p; p += HH*sizeof(double);
    double* rec   = (double*)p; p += NBH*sizeof(double);           // 16.8 MB
    double* attrA = (double*)p; p += NBH*sizeof(double);           // 16.8 MB
    double* attrB = (double*)p; p += NBH*sizeof(double);           // 16.8 MB
    double* gated = (double*)p; p += NBH*sizeof(double);           // 16.8 MB
    float*  spkcnt= (float*)p;  p += NBH*sizeof(float);            // 8.4 MB
    double* mu    = (double*)p; p += BB*sizeof(double);
    double* rstd  = (double*)p; p += BB*sizeof(double);
    // total ~84 MB (<101 MB proven in R3)

    hipMemsetAsync(rec,    0, NBH*sizeof(double), stream);
    hipMemsetAsync(attrA,  0, NBH*sizeof(double), stream);
    hipMemsetAsync(spkcnt, 0, NBH*sizeof(float),  stream);

    dim3 blk(256);
    dim3 g_wpf(HH/64, DD/64);   // 32 x 16
    k_wpf<<<g_wpf, blk, 0, stream>>>(Wp, Wfc, Wpf);
    k_bpf<<<HH/256, blk, 0, stream>>>(bp, Wfc, bfc, bpf);

    dim3 g_step(HH/64, BB/64);  // 32 x 16
    double* ain  = attrA;
    double* aout = attrB;
    for (int t = 0; t < TT; ++t) {
        k_update <<<g_step, blk, 0, stream>>>(x, t, Wpf, bpf, rec);
        k_lnstats<<<BB,     blk, 0, stream>>>(rec, mu, rstd);
        k_gate   <<<g_step, blk, 0, stream>>>(rec, mu, rstd, gamma, beta, Wg, bg, gated);
        k_current<<<g_step, blk, 0, stream>>>(gated, Wenc, ain, Wrec, benc, brec, aout, spkcnt);
        double* tmp = ain; ain = aout; aout = tmp;
    }
    // final attractor state in `ain`

    dim3 g_ro(OO/64, BB/64);    // 16 x 16
    k_readout<<<g_ro, blk, 0, stream>>>(spkcnt, Wro, bro, out);
    k_d2f<<<NBH/256, blk, 0, stream>>>(rec, out + (long)BB*OO);
    k_d2f<<<NBH/256, blk, 0, stream>>>(ain, out + (long)BB*OO + NBH);
}